// Round 1
// baseline (300.140 us; speedup 1.0000x reference)
//
#include <hip/hip_runtime.h>

// Problem constants: T=2048, B=8, IN=1024, OUT=1024, N_MODULES=16, K=2
#define T_DIM   2048
#define B_DIM   8
#define IN_DIM  1024
#define OUT_DIM 1024
#define NMOD    16
#define KSLOT   2

// 8-phase 256x256 schedule (m201 template): BK=64, 8 waves (2M x 4N), 512 thr
#define BM 256
#define BN 256
#define BK 64
#define NT (IN_DIM / BK)            // 16 K-tiles
#define AS_STRIDE (B_DIM * IN_DIM)  // 8192

typedef __bf16 bf16x8 __attribute__((ext_vector_type(8)));
typedef float  f32x4  __attribute__((ext_vector_type(4)));
typedef unsigned short ushort8 __attribute__((ext_vector_type(8)));

typedef const __attribute__((address_space(1))) void* gptr_t;
typedef __attribute__((address_space(3))) void* lptr_t;

__device__ __forceinline__ void async_load16(const void* gp, void* lp) {
  __builtin_amdgcn_global_load_lds((gptr_t)gp, (lptr_t)lp, 16, 0, 0);
}

// fp32 -> bf16 round-to-nearest-even (inputs have no NaNs)
__device__ __forceinline__ unsigned short f2bf_rne(float f) {
  unsigned int u = __float_as_uint(f);
  u += 0x7fffu + ((u >> 16) & 1u);
  return (unsigned short)(u >> 16);
}

// Streaming prepass: x [T][B][IN] fp32 -> xb same layout bf16; w -> wb bf16.
__global__ __launch_bounds__(256) void convert_bf16(
    const float* __restrict__ x, const float* __restrict__ w,
    unsigned short* __restrict__ xb, unsigned short* __restrict__ wb) {
  const long tid = (long)blockIdx.x * blockDim.x + threadIdx.x;
  const long XV = (long)T_DIM * B_DIM * IN_DIM / 8;
  const float4* src;
  unsigned short* dst;
  long v;
  if (tid < XV) { v = tid;      src = (const float4*)x; dst = xb; }
  else          { v = tid - XV; src = (const float4*)w; dst = wb; }
  float4 a = src[2 * v];
  float4 c = src[2 * v + 1];
  ushort8 o;
  o[0] = f2bf_rne(a.x); o[1] = f2bf_rne(a.y); o[2] = f2bf_rne(a.z); o[3] = f2bf_rne(a.w);
  o[4] = f2bf_rne(c.x); o[5] = f2bf_rne(c.y); o[6] = f2bf_rne(c.z); o[7] = f2bf_rne(c.w);
  *(ushort8*)(dst + v * 8) = o;
}

#define S_BARRIER()  asm volatile("s_barrier" ::: "memory")
#define WAIT_LGKM0() asm volatile("s_waitcnt lgkmcnt(0)" ::: "memory")

// One GEMM per blockIdx.z slot (b,k): C[t,o] = sum_i xb[t][b][i] * wb[sel[b,k]][o][i]
//
// 8-phase schedule, 2 barriers/phase (except P3), counted vmcnt (never 0 in
// steady state). LDS: 2 dbuf x (A 256x64 + B 256x64) bf16 = 128 KiB, stored
// as 16-B chunks with source-side XOR swizzle (slot s of row r holds colgrp
// s^(r&7)); read via slot = gsel^(row&7) -> conflict-free (verified 0 prev).
//
// Half-tile "regions" = union over waves of per-phase reads:
//   A-a = rows [0,64)u[128,192)      (read P0: mi0-3, all waves)
//   A-b = rows [64,128)u[192,256)    (read P2: mi4-7)
//   B-a = rows ==[0,32) mod 64       (read P0: ni0-1; b0 held in regs to P3)
//   B-b = rows ==[32,64) mod 64      (read P1: ni2-3)
// Staging order per K-tile: [A-a, B-b, A-b, B-a]; group t stages (t+1).Ba at
// P0 (into nxt buf) and (t+2).{Aa,Bb,Ab} at P1/P2/P3 (into cur buf) -- each
// region overwritten one barrier AFTER its last reader. vmcnt(6) at P3 leaves
// exactly the 3 newest half-stages in flight => K-tile t+1 fully landed.
__global__ __launch_bounds__(512, 2) void gemm_mod(
    const unsigned short* __restrict__ xb, const unsigned short* __restrict__ wb,
    const int* __restrict__ sel, float* __restrict__ out) {
  __shared__ alignas(16) unsigned short As[2][BM * BK];   // 64 KiB
  __shared__ alignas(16) unsigned short Bs[2][BN * BK];   // 64 KiB

  const int nt = blockIdx.x;           // OUT tile: 0..3
  const int mt = blockIdx.y;           // T tile:   0..7
  const int bk = blockIdx.z;           // 0..15 -> (b, k)
  const int b  = bk >> 1;
  const int ks = bk & 1;
  const int expert = sel[bk];

  const unsigned short* Ab = xb + ((long)mt * BM * B_DIM + b) * IN_DIM;
  const unsigned short* Bb = wb + ((long)expert * OUT_DIM + (long)nt * BN) * IN_DIM;

  const int tid  = threadIdx.x;
  const int lane = tid & 63;
  const int lm   = lane & 15;          // MFMA m/n index
  const int kg   = lane >> 4;          // MFMA k-group (0..3)
  const int rsw  = lm & 7;             // row-derived swizzle term
  const int w    = tid >> 6;           // 8 waves: 2(M) x 4(N)
  const int wm   = (w >> 2) * 128;     // wave tile 128 x 64
  const int wn   = (w & 3) * 64;

  // Staging offsets [j][h] (2 x global_load_lds per half-tile per thread).
  // A half h: chunks {h*512+tid} u {1024+h*512+tid} -> rows [h*64,h*64+64) of
  // each 128-row block.  B half h: 4 spans of 32 rows (rows == [h*32,(h+1)*32)
  // mod 64).  Source col-group pre-swizzled: g = (c&7)^(r&7); LDS dest linear.
  int aoff[2][2], alds[2][2], boff[2][2], blds[2][2];
  #pragma unroll
  for (int j = 0; j < 2; ++j) {
    #pragma unroll
    for (int h = 0; h < 2; ++h) {
      const int c = j * 1024 + h * 512 + tid;
      const int r = c >> 3, g = (c & 7) ^ (r & 7);
      aoff[j][h] = r * AS_STRIDE + g * 8;
      alds[j][h] = c * 8;
      const int cc = j * 512 + tid;
      const int c2 = (cc >> 8) * 512 + h * 256 + (cc & 255);
      const int r2 = c2 >> 3, g2 = (c2 & 7) ^ (r2 & 7);
      boff[j][h] = r2 * IN_DIM + g2 * 8;
      blds[j][h] = c2 * 8;
    }
  }

#define STAGE_A(d, kt, h) do { \
    async_load16(Ab + aoff[0][h] + (kt) * BK, &As[d][alds[0][h]]); \
    async_load16(Ab + aoff[1][h] + (kt) * BK, &As[d][alds[1][h]]); } while (0)
#define STAGE_B(d, kt, h) do { \
    async_load16(Bb + boff[0][h] + (kt) * BK, &Bs[d][blds[0][h]]); \
    async_load16(Bb + boff[1][h] + (kt) * BK, &Bs[d][blds[1][h]]); } while (0)
#define LDA(d, row, gs) (*(const bf16x8*)&As[d][((((row) << 3) + ((gs) ^ rsw)) << 3)])
#define LDB(d, row, gs) (*(const bf16x8*)&Bs[d][((((row) << 3) + ((gs) ^ rsw)) << 3)])

  f32x4 acc[8][4];
  const f32x4 z = {0.f, 0.f, 0.f, 0.f};
  #pragma unroll
  for (int i = 0; i < 8; ++i)
    #pragma unroll
    for (int j = 0; j < 4; ++j) acc[i][j] = z;

  // ---- prologue: K0 all 4 halves + K1 first 3 (order: Aa, Bb, Ab, Ba) ----
  STAGE_A(0, 0, 0);
  STAGE_B(0, 0, 1);
  STAGE_A(0, 0, 1);
  STAGE_B(0, 0, 0);
  STAGE_A(1, 1, 0);
  STAGE_B(1, 1, 1);
  STAGE_A(1, 1, 1);
  asm volatile("s_waitcnt vmcnt(6)" ::: "memory");   // K0 landed; K1 x3 in flight
  S_BARRIER();

  for (int t = 0; t < NT; ++t) {
    const int cur = t & 1;
    const int nxt = cur ^ 1;
    bf16x8 af[4][2], b0[2][2], b1[2][2];

    // ===== P0: read A-a (8) + B-a (4); stage (t+1).Ba -> nxt =====
    #pragma unroll
    for (int mi = 0; mi < 4; ++mi)
      #pragma unroll
      for (int kst = 0; kst < 2; ++kst)
        af[mi][kst] = LDA(cur, wm + mi * 16 + lm, kst * 4 + kg);
    #pragma unroll
    for (int ni = 0; ni < 2; ++ni)
      #pragma unroll
      for (int kst = 0; kst < 2; ++kst)
        b0[ni][kst] = LDB(cur, wn + ni * 16 + lm, kst * 4 + kg);
    if (t + 1 < NT) STAGE_B(nxt, t + 1, 0);
    S_BARRIER();
    WAIT_LGKM0();
    __builtin_amdgcn_s_setprio(1);
    #pragma unroll
    for (int mi = 0; mi < 4; ++mi)
      #pragma unroll
      for (int ni = 0; ni < 2; ++ni)
        #pragma unroll
        for (int kst = 0; kst < 2; ++kst)
          acc[mi][ni] = __builtin_amdgcn_mfma_f32_16x16x32_bf16(
              af[mi][kst], b0[ni][kst], acc[mi][ni], 0, 0, 0);
    __builtin_amdgcn_s_setprio(0);
    S_BARRIER();

    // ===== P1: read B-b (4); stage (t+2).Aa -> cur =====
    #pragma unroll
    for (int nj = 0; nj < 2; ++nj)
      #pragma unroll
      for (int kst = 0; kst < 2; ++kst)
        b1[nj][kst] = LDB(cur, wn + (2 + nj) * 16 + lm, kst * 4 + kg);
    if (t + 2 < NT) STAGE_A(cur, t + 2, 0);
    S_BARRIER();
    WAIT_LGKM0();
    __builtin_amdgcn_s_setprio(1);
    #pragma unroll
    for (int mi = 0; mi < 4; ++mi)
      #pragma unroll
      for (int nj = 0; nj < 2; ++nj)
        #pragma unroll
        for (int kst = 0; kst < 2; ++kst)
          acc[mi][2 + nj] = __builtin_amdgcn_mfma_f32_16x16x32_bf16(
              af[mi][kst], b1[nj][kst], acc[mi][2 + nj], 0, 0, 0);
    __builtin_amdgcn_s_setprio(0);
    S_BARRIER();

    // ===== P2: read A-b (8); stage (t+2).Bb -> cur =====
    #pragma unroll
    for (int mi = 0; mi < 4; ++mi)
      #pragma unroll
      for (int kst = 0; kst < 2; ++kst)
        af[mi][kst] = LDA(cur, wm + 64 + mi * 16 + lm, kst * 4 + kg);
    if (t + 2 < NT) STAGE_B(cur, t + 2, 1);
    S_BARRIER();
    WAIT_LGKM0();
    __builtin_amdgcn_s_setprio(1);
    #pragma unroll
    for (int mi = 0; mi < 4; ++mi)
      #pragma unroll
      for (int nj = 0; nj < 2; ++nj)
        #pragma unroll
        for (int kst = 0; kst < 2; ++kst)
          acc[4 + mi][2 + nj] = __builtin_amdgcn_mfma_f32_16x16x32_bf16(
              af[mi][kst], b1[nj][kst], acc[4 + mi][2 + nj], 0, 0, 0);
    __builtin_amdgcn_s_setprio(0);
    S_BARRIER();

    // ===== P3: no reads (b0 held); stage (t+2).Ab -> cur; vmcnt gate =====
    if (t + 2 < NT) STAGE_A(cur, t + 2, 1);
    __builtin_amdgcn_s_setprio(1);
    #pragma unroll
    for (int mi = 0; mi < 4; ++mi)
      #pragma unroll
      for (int ni = 0; ni < 2; ++ni)
        #pragma unroll
        for (int kst = 0; kst < 2; ++kst)
          acc[4 + mi][ni] = __builtin_amdgcn_mfma_f32_16x16x32_bf16(
              af[mi][kst], b0[ni][kst], acc[4 + mi][ni], 0, 0, 0);
    __builtin_amdgcn_s_setprio(0);
    if (t < NT - 2) {
      asm volatile("s_waitcnt vmcnt(6)" ::: "memory");  // 3 newest halves fly
    } else {
      asm volatile("s_waitcnt vmcnt(0)" ::: "memory");  // tail drain
    }
    S_BARRIER();
  }

  // Epilogue. C/D layout (m89-verified): col = lane&15, row = (lane>>4)*4 + reg
  const int row0 = mt * BM + wm + kg * 4;
  const int col0 = nt * BN + wn + lm;
  #pragma unroll
  for (int mi = 0; mi < 8; ++mi) {
    #pragma unroll
    for (int r = 0; r < 4; ++r) {
      const int t_row = row0 + mi * 16 + r;
      float* po = out + (long)t_row * (B_DIM * KSLOT * OUT_DIM)
                      + b * (KSLOT * OUT_DIM) + ks * OUT_DIM + col0;
      #pragma unroll
      for (int ni = 0; ni < 4; ++ni)
        po[ni * 16] = acc[mi][ni][r];
    }
  }
#undef STAGE_A
#undef STAGE_B
#undef LDA
#undef LDB
}

extern "C" void kernel_launch(void* const* d_in, const int* in_sizes, int n_in,
                              void* d_out, int out_size, void* d_ws, size_t ws_size,
                              hipStream_t stream) {
  const float* x   = (const float*)d_in[0];   // [T][B][IN] fp32
  const int*   sel = (const int*)d_in[1];     // [B][K] int32
  const float* w   = (const float*)d_in[2];   // [NMOD][OUT][IN] fp32
  float* out = (float*)d_out;                 // [T][B][K*OUT] fp32

  unsigned short* xb = (unsigned short*)d_ws;                 // 32 MiB bf16 [T][B][IN]
  unsigned short* wb = xb + (long)T_DIM * B_DIM * IN_DIM;     // 32 MiB bf16 [NMOD][OUT][IN]

  const long total_vecs =
      ((long)T_DIM * B_DIM * IN_DIM + (long)NMOD * OUT_DIM * IN_DIM) / 8;
  convert_bf16<<<dim3((unsigned)((total_vecs + 255) / 256)), 256, 0, stream>>>(x, w, xb, wb);

  dim3 ggrid(OUT_DIM / BN, T_DIM / BM, B_DIM * KSLOT);
  gemm_mod<<<ggrid, 512, 0, stream>>>(xb, wb, sel, out);
}